// Round 1
// 2293.112 us; speedup vs baseline: 1.0407x; 1.0407x over previous
//
#include <hip/hip_runtime.h>

typedef unsigned short ushort_t;
typedef short short8 __attribute__((ext_vector_type(8)));
typedef unsigned short ushort8 __attribute__((ext_vector_type(8)));
typedef float floatx4 __attribute__((ext_vector_type(4)));

#define NB 256   // batch
#define TT 128   // time steps
#define II 512   // input dim
#define HH 512   // hidden dim
#define NTH (NB * TT * HH)   // 16,777,216 elements per output tensor
#define RBLK 256             // recurrence grid blocks (1 per CU)

__device__ __forceinline__ float bf2f(ushort_t u) {
    union { unsigned int i; float f; } v;
    v.i = ((unsigned int)u) << 16;
    return v.f;
}
__device__ __forceinline__ ushort_t f2bf(float f) {
    union { float f; unsigned int i; } v;
    v.f = f;
    unsigned int u = v.i;
    u += 0x7fffu + ((u >> 16) & 1u);   // round-to-nearest-even
    return (ushort_t)(u >> 16);
}
__device__ __forceinline__ float sigmoid_(float x) { return 1.f / (1.f + __expf(-x)); }
__device__ __forceinline__ float tanh_fast(float x) {
    // 1 - 2/(e^{2x}+1); exp overflow -> inf -> 1 (correct saturation)
    return 1.f - 2.f / (__expf(2.f * x) + 1.f);
}
__device__ __forceinline__ float mish_fast(float v) {
    // v * tanh(softplus(v)) == v * t/(t+2), t = e*(e+2), e = exp(v) (exact)
    float e = __expf(fminf(v, 20.f));
    float t = e * (e + 2.f);
    return v * t / (t + 2.f);
}

// ---------------------------------------------------------------------------
// fp32 -> bf16 bulk convert, 8 elems/thread.
// ---------------------------------------------------------------------------
__global__ __launch_bounds__(256) void cvt_bf16_kernel(
    const float* __restrict__ src, ushort_t* __restrict__ dst, int n8)
{
    int i = blockIdx.x * 256 + threadIdx.x;
    if (i >= n8) return;
    const float4* s = (const float4*)src;
    float4 a = s[i * 2];
    float4 b = s[i * 2 + 1];
    ushort8 v;
    v[0] = f2bf(a.x); v[1] = f2bf(a.y); v[2] = f2bf(a.z); v[3] = f2bf(a.w);
    v[4] = f2bf(b.x); v[5] = f2bf(b.y); v[6] = f2bf(b.z); v[7] = f2bf(b.w);
    ((ushort8*)dst)[i] = v;
}

// ---------------------------------------------------------------------------
// Init: hp0 = bf16(hx[:,0,:]); b_comb = b_ih + b_hh; zero group flags.
// ---------------------------------------------------------------------------
__global__ __launch_bounds__(256) void init_kernel(
    const float* __restrict__ hx,
    const float* __restrict__ b_ih, const float* __restrict__ b_hh,
    ushort_t* __restrict__ hp0, float* __restrict__ b_comb,
    unsigned* __restrict__ flags)
{
    int idx = blockIdx.x * 256 + threadIdx.x;   // over NB*HH
    int m = idx >> 9;
    int h = idx & 511;
    hp0[idx] = f2bf(hx[(size_t)m * TT * HH + h]);
    if (idx < 4 * HH) b_comb[idx] = b_ih[idx] + b_hh[idx];
    if (idx < RBLK * 16) flags[idx] = 0u;   // 256 flags, 64 B apart
}

// ---------------------------------------------------------------------------
// LDS-tiled bf16 GEMM: C[M,N] = A[M,512] * B[N,512]^T + bias, 128x128 tiles.
// bm = bx & 255 (A-tile), bn = bx >> 8 -> bn-siblings stride-256 = same XCD,
// so an A-tile is fetched from HBM once per XCD.
// MODE 0: scatter-store bf16 Gx[t][n][col] (A-row = n*128+t), bias=b_comb.
// MODE 1: out fp32 = mish(acc + bias) straight store.
// ---------------------------------------------------------------------------
template<int MODE>
__global__ __launch_bounds__(256, 2) void gemm_kernel(
    const ushort_t* __restrict__ A, const ushort_t* __restrict__ B,
    const float* __restrict__ bias,
    ushort_t* __restrict__ gx_lo, ushort_t* __restrict__ gx_hi,
    float* __restrict__ outp)
{
    __shared__ ushort_t As[128 * 32];
    __shared__ ushort_t Bs[128 * 32];
    const int tid  = threadIdx.x;
    const int wv   = tid >> 6;
    const int lane = tid & 63;
    const int q    = lane >> 4;
    const int l15  = lane & 15;
    const int bm   = blockIdx.x & 255;
    const int bn   = blockIdx.x >> 8;
    const int mh   = (wv >> 1) * 64;
    const int nh   = (wv & 1) * 64;

    const ushort_t* Ab = A + (size_t)bm * 128 * 512;
    const ushort_t* Bb = B + (size_t)bn * 128 * 512;

    const int r0 = tid >> 2;        // 0..63
    const int r1 = r0 + 64;         // 64..127
    const int k8 = (tid & 3) * 8;

    floatx4 acc[4][4];
#pragma unroll
    for (int i = 0; i < 4; ++i)
#pragma unroll
        for (int j = 0; j < 4; ++j) acc[i][j] = (floatx4){0.f, 0.f, 0.f, 0.f};

    for (int kt = 0; kt < 16; ++kt) {
        const int kc = kt * 32 + k8;
        short8 a0 = *(const short8*)(Ab + (size_t)r0 * 512 + kc);
        short8 a1 = *(const short8*)(Ab + (size_t)r1 * 512 + kc);
        short8 b0 = *(const short8*)(Bb + (size_t)r0 * 512 + kc);
        short8 b1 = *(const short8*)(Bb + (size_t)r1 * 512 + kc);
        __syncthreads();
        *(short8*)&As[r0 * 32 + k8] = a0;
        *(short8*)&As[r1 * 32 + k8] = a1;
        *(short8*)&Bs[r0 * 32 + k8] = b0;
        *(short8*)&Bs[r1 * 32 + k8] = b1;
        __syncthreads();
        short8 af[4], bfr[4];
#pragma unroll
        for (int s = 0; s < 4; ++s) af[s]  = *(const short8*)&As[(mh + s * 16 + l15) * 32 + q * 8];
#pragma unroll
        for (int s = 0; s < 4; ++s) bfr[s] = *(const short8*)&Bs[(nh + s * 16 + l15) * 32 + q * 8];
#pragma unroll
        for (int i = 0; i < 4; ++i)
#pragma unroll
            for (int j = 0; j < 4; ++j)
                acc[i][j] = __builtin_amdgcn_mfma_f32_16x16x32_bf16(af[i], bfr[j], acc[i][j], 0, 0, 0);
    }

    float bv[4];
#pragma unroll
    for (int j = 0; j < 4; ++j) bv[j] = bias[bn * 128 + nh + j * 16 + l15];

#pragma unroll
    for (int i = 0; i < 4; ++i) {
        const int rowb = bm * 128 + mh + i * 16 + q * 4;
#pragma unroll
        for (int r = 0; r < 4; ++r) {
            const int row = rowb + r;
            if (MODE == 0) {
                const int n = row >> 7, t = row & 127;
                ushort_t* base = (t < 64) ? (gx_lo + ((size_t)t * NB + n) * 2048)
                                          : (gx_hi + ((size_t)(t - 64) * NB + n) * 2048);
#pragma unroll
                for (int j = 0; j < 4; ++j)
                    base[bn * 128 + nh + j * 16 + l15] = f2bf(acc[i][j][r] + bv[j]);
            } else {
                float* ob = outp + (size_t)row * 512;
#pragma unroll
                for (int j = 0; j < 4; ++j)
                    ob[bn * 128 + nh + j * 16 + l15] = mish_fast(acc[i][j][r] + bv[j]);
            }
        }
    }
}

// ---------------------------------------------------------------------------
// Persistent recurrence with PER-GROUP producer flags (no global barrier).
// 256 blocks (1/CU) x 256 threads. Block (bm,bh) owns batch rows bm*16..+15,
// hidden cols bh*32..+31. The only cross-block dependence is along the hidden
// dimension, i.e. among the 16 blocks sharing bm -> 16 independent groups.
//
// h_t is written once into hsb[(n*TT+t)*HH] (write-once, no WAR hazard);
// consumers of step t read h_{t-1} straight from hsb. Producer protocol per
// step: __syncthreads (drains all waves' stores, vmcnt 0) -> release fence
// (buffer_wbl2: flush h stores to L3, the cross-XCD coherence point) ->
// relaxed agent store flag[block]=t+1 (sc1, lands in L3, own cacheline: no
// RMW serialization). Consumer: lanes 0..15 poll the group's 16 flags
// (relaxed agent loads, sc1 -> always read L3) -> __syncthreads -> acquire
// fence (buffer_inv) -> plain hsb reads now miss L1/L2 and hit fresh L3 data.
// W_hh fragments (4 gates x 32 cols x K=512) live in 128 VGPRs all 128 steps.
// ---------------------------------------------------------------------------
__global__ __launch_bounds__(256, 1) void recur_kernel(
    const float* __restrict__ Whh,       // (2048,512) fp32
    const int* __restrict__ is_init,     // (NB,TT)
    const float* __restrict__ cx,        // (NB,TT,HH) fp32
    const ushort_t* __restrict__ gx_lo,  // (64,NB,2048) bf16
    const ushort_t* __restrict__ gx_hi,  // (64,NB,2048) bf16
    ushort_t* __restrict__ hp0,          // (NB,HH) bf16: h0 in, h_T out
    ushort_t* __restrict__ hsb,          // (NB,TT,HH) bf16 all h_t
    float* __restrict__ c_out,           // (NB,HH) fp32 final c
    unsigned* __restrict__ flags)        // RBLK flags, 64 B apart
{
    __shared__ ushort_t hA[16 * 520];        // pad: row stride 520 shorts
    __shared__ float gbuf[4][16][32];

    const int tid  = threadIdx.x;
    const int gate = tid >> 6;
    const int lane = tid & 63;
    const int q    = lane >> 4;
    const int l15  = lane & 15;
    const int bm   = blockIdx.x >> 4;     // group: 0..15
    const int bh   = blockIdx.x & 15;     // member within group
    const int h0   = bh * 32;

    // ---- preload W_hh B-fragments (fp32 -> bf16) into registers: 128 VGPRs
    short8 bfrag[2][16];
#pragma unroll
    for (int j = 0; j < 2; ++j) {
        const float* wr = Whh + (size_t)(gate * 512 + h0 + j * 16 + l15) * 512;
#pragma unroll
        for (int kk = 0; kk < 16; ++kk) {
            const float* p = wr + kk * 32 + q * 8;
            float4 f0 = *(const float4*)p;
            float4 f1 = *(const float4*)(p + 4);
            short8 v;
            v[0] = (short)f2bf(f0.x); v[1] = (short)f2bf(f0.y);
            v[2] = (short)f2bf(f0.z); v[3] = (short)f2bf(f0.w);
            v[4] = (short)f2bf(f1.x); v[5] = (short)f2bf(f1.y);
            v[6] = (short)f2bf(f1.z); v[7] = (short)f2bf(f1.w);
            bfrag[j][kk] = v;
        }
    }

    // ---- c-state in registers: thread owns elems (n_c, h0+hc), (n_c, h0+hc+1)
    const int m_c = tid >> 4;             // 0..15
    const int hc  = (tid * 2) & 31;       // 0,2,..,30
    const int n_c = bm * 16 + m_c;
    float2 c2 = *(const float2*)(cx + (size_t)n_c * TT * HH + h0 + hc);

    unsigned* myflag = flags + (size_t)blockIdx.x * 16;

    for (int t = 0; t < TT; ++t) {
        // prefetch this step's Gx early (read-only, written before this
        // kernel: safe to load pre-fence; values live in registers)
        const ushort_t* gxp = ((t < 64) ? (gx_lo + (size_t)t * NB * 2048)
                                        : (gx_hi + (size_t)(t - 64) * NB * 2048))
                              + (size_t)n_c * 2048 + h0 + hc;
        ushort2 gxu[4];
#pragma unroll
        for (int g = 0; g < 4; ++g) gxu[g] = *(const ushort2*)(gxp + g * 512);

        // ---- wait for the 16 group peers to have published h_{t-1}
        if (t > 0) {
            if (tid < 16) {
                unsigned* fp = flags + (size_t)(bm * 16 + tid) * 16;
                while (__hip_atomic_load(fp, __ATOMIC_RELAXED,
                                         __HIP_MEMORY_SCOPE_AGENT) < (unsigned)t)
                    __builtin_amdgcn_s_sleep(1);
            }
            __syncthreads();
            __builtin_amdgcn_fence(__ATOMIC_ACQUIRE, "agent");  // buffer_inv
        }

        // stage h-tile (16 x 512) to LDS, rows zeroed where is_init==1
#pragma unroll
        for (int i = 0; i < 4; ++i) {
            int idx = i * 256 + tid;
            int row = idx >> 6;
            int cc  = (idx & 63) * 8;
            int n   = bm * 16 + row;
            ushort8 v = {0, 0, 0, 0, 0, 0, 0, 0};
            if (!is_init[n * TT + t]) {
                const ushort_t* p = t ? (hsb + ((size_t)n * TT + (t - 1)) * HH + cc)
                                      : (hp0 + (size_t)n * HH + cc);
                v = *(const ushort8*)p;
            }
            *(ushort8*)&hA[row * 520 + cc] = v;
        }
        __syncthreads();

        floatx4 a0 = {0.f, 0.f, 0.f, 0.f}, a1 = {0.f, 0.f, 0.f, 0.f};
#pragma unroll
        for (int kk = 0; kk < 16; ++kk) {
            short8 af = *(const short8*)&hA[l15 * 520 + kk * 32 + q * 8];
            a0 = __builtin_amdgcn_mfma_f32_16x16x32_bf16(af, bfrag[0][kk], a0, 0, 0, 0);
            a1 = __builtin_amdgcn_mfma_f32_16x16x32_bf16(af, bfrag[1][kk], a1, 0, 0, 0);
        }
#pragma unroll
        for (int r = 0; r < 4; ++r) {
            gbuf[gate][q * 4 + r][l15]      = a0[r];
            gbuf[gate][q * 4 + r][16 + l15] = a1[r];
        }
        __syncthreads();

        // pointwise cell update for this thread's 2 elements
        float g4[4][2];
#pragma unroll
        for (int g = 0; g < 4; ++g) {
            g4[g][0] = bf2f(gxu[g].x) + gbuf[g][m_c][hc];
            g4[g][1] = bf2f(gxu[g].y) + gbuf[g][m_c][hc + 1];
        }
        const int rst = is_init[n_c * TT + t];
        float cp0 = rst ? 0.f : c2.x;
        float cp1 = rst ? 0.f : c2.y;
        float cn0 = sigmoid_(g4[1][0]) * cp0 + sigmoid_(g4[0][0]) * tanh_fast(g4[2][0]);
        float cn1 = sigmoid_(g4[1][1]) * cp1 + sigmoid_(g4[0][1]) * tanh_fast(g4[2][1]);
        float hn0 = sigmoid_(g4[3][0]) * tanh_fast(cn0);
        float hn1 = sigmoid_(g4[3][1]) * tanh_fast(cn1);
        c2.x = cn0; c2.y = cn1;

        ushort2 hb;
        hb.x = f2bf(hn0); hb.y = f2bf(hn1);
        *(ushort2*)(hsb + ((size_t)n_c * TT + t) * HH + h0 + hc) = hb;
        if (t == TT - 1)
            *(ushort2*)(hp0 + (size_t)n_c * HH + h0 + hc) = hb;   // final h for broadcast

        // ---- publish h_t to the group (skip after last step: kernel-end
        //      implicit release covers gemm<1>/broadcast consumers)
        if (t != TT - 1) {
            __syncthreads();              // all waves' h stores drained to L2
            if (tid == 0) {
                __builtin_amdgcn_fence(__ATOMIC_RELEASE, "agent");  // wbl2 -> L3
                __hip_atomic_store(myflag, (unsigned)(t + 1), __ATOMIC_RELAXED,
                                   __HIP_MEMORY_SCOPE_AGENT);
            }
        }
    }

    // final c
    *(float2*)(c_out + (size_t)n_c * HH + h0 + hc) = c2;
}

// ---------------------------------------------------------------------------
// Broadcast h_T / c_T to (NB,TT,HH) fp32.
// ---------------------------------------------------------------------------
__global__ __launch_bounds__(256) void broadcast_kernel(
    const ushort_t* __restrict__ hT,   // (NB,HH) bf16
    const float* __restrict__ cT,      // (NB,HH) fp32
    float* __restrict__ h_rep, float* __restrict__ c_rep)
{
    size_t idx  = (size_t)blockIdx.x * 256 + threadIdx.x;
    size_t flat = idx * 8;
    int m = (int)(flat >> 16);
    int h = (int)(flat & 511);

    const ushort_t* hp = hT + (size_t)m * HH + h;
    const float*    cp = cT + (size_t)m * HH + h;

    float4 h0v, h1v, c0v, c1v;
    h0v.x = bf2f(hp[0]); h0v.y = bf2f(hp[1]); h0v.z = bf2f(hp[2]); h0v.w = bf2f(hp[3]);
    h1v.x = bf2f(hp[4]); h1v.y = bf2f(hp[5]); h1v.z = bf2f(hp[6]); h1v.w = bf2f(hp[7]);
    c0v.x = cp[0]; c0v.y = cp[1]; c0v.z = cp[2]; c0v.w = cp[3];
    c1v.x = cp[4]; c1v.y = cp[5]; c1v.z = cp[6]; c1v.w = cp[7];

    *(float4*)(h_rep + flat)     = h0v;
    *(float4*)(h_rep + flat + 4) = h1v;
    *(float4*)(c_rep + flat)     = c0v;
    *(float4*)(c_rep + flat + 4) = c1v;
}

// ---------------------------------------------------------------------------
extern "C" void kernel_launch(void* const* d_in, const int* in_sizes, int n_in,
                              void* d_out, int out_size, void* d_ws, size_t ws_size,
                              hipStream_t stream) {
    const float* x      = (const float*)d_in[0];
    const int*   isini  = (const int*)d_in[1];
    const float* hx     = (const float*)d_in[2];
    const float* cx     = (const float*)d_in[3];
    const float* W_ih   = (const float*)d_in[4];
    const float* W_hh   = (const float*)d_in[5];
    const float* b_ih   = (const float*)d_in[6];
    const float* b_hh   = (const float*)d_in[7];
    const float* W_out  = (const float*)d_in[8];
    const float* b_out  = (const float*)d_in[9];

    float* out   = (float*)d_out;
    float* h_rep = out + (size_t)NTH;
    float* c_rep = out + (size_t)2 * NTH;

    // Staging in dead d_out regions (stream-ordered overwrites):
    //  Gx (t<64)  -> out0 region  (consumed by recur; overwritten by outproj)
    //  Gx (t>=64) -> c_rep region (consumed by recur; overwritten by broadcast)
    //  hsb        -> h_rep lower half (written by recur; consumed by outproj)
    //  xb         -> h_rep upper half (consumed by Gx GEMM)
    ushort_t* gx_lo = (ushort_t*)out;
    ushort_t* gx_hi = (ushort_t*)c_rep;
    ushort_t* hsb   = (ushort_t*)h_rep;
    ushort_t* xb    = (ushort_t*)h_rep + (size_t)NTH;

    // workspace (~3.6 MiB)
    char* wsb = (char*)d_ws;
    ushort_t* hp0     = (ushort_t*)wsb;                                   // 256 KiB
    unsigned* flags   = (unsigned*)(wsb + (size_t)NB * HH * 2);           // (old hp1 slot) 16 KiB
    float*    c_state = (float*)(wsb + (size_t)2 * NB * HH * 2);          // 512 KiB
    float*    b_comb  = (float*)(wsb + (size_t)2 * NB * HH * 2
                                     + (size_t)NB * HH * 4);              // 8 KiB
    ushort_t* woutb   = (ushort_t*)(wsb + (size_t)2 * NB * HH * 2
                                        + (size_t)NB * HH * 4 + 4 * HH * 4); // 512 KiB
    ushort_t* wihb    = woutb + (size_t)HH * HH;                          // 2 MiB

    // --- prep ---
    cvt_bf16_kernel<<<NTH / 8 / 256, 256, 0, stream>>>(x, xb, NTH / 8);
    cvt_bf16_kernel<<<4 * HH * II / 8 / 256, 256, 0, stream>>>(W_ih, wihb, 4 * HH * II / 8);
    cvt_bf16_kernel<<<HH * HH / 8 / 256, 256, 0, stream>>>(W_out, woutb, HH * HH / 8);
    init_kernel<<<NB * HH / 256, 256, 0, stream>>>(hx, b_ih, b_hh, hp0, b_comb, flags);

    // --- Gx = x @ W_ih^T + (b_ih + b_hh), bf16, layout (t, n, 2048) ---
    gemm_kernel<0><<<16 * 256, 256, 0, stream>>>(xb, wihb, b_comb, gx_lo, gx_hi, nullptr);

    // --- persistent recurrence, per-group flag sync (no global barrier) ---
    recur_kernel<<<RBLK, 256, 0, stream>>>(W_hh, isini, cx, gx_lo, gx_hi,
                                           hp0, hsb, c_state, flags);

    // --- out0 = mish(hs @ W_out^T + b_out) ---
    gemm_kernel<1><<<4 * 256, 256, 0, stream>>>(hsb, woutb, b_out, nullptr, nullptr, out);

    // --- h_rep / c_rep broadcasts (final h in hp0) ---
    broadcast_kernel<<<NTH / 8 / 256, 256, 0, stream>>>(hp0, c_state, h_rep, c_rep);
}

// Round 2
// 846.983 us; speedup vs baseline: 2.8176x; 2.7074x over previous
//
#include <hip/hip_runtime.h>

typedef unsigned short ushort_t;
typedef short short8 __attribute__((ext_vector_type(8)));
typedef unsigned short ushort8 __attribute__((ext_vector_type(8)));
typedef float floatx4 __attribute__((ext_vector_type(4)));

#define NB 256   // batch
#define TT 128   // time steps
#define II 512   // input dim
#define HH 512   // hidden dim
#define NTH (NB * TT * HH)   // 16,777,216 elements per output tensor
#define RBLK 256             // recurrence grid blocks (1 per CU)

__device__ __forceinline__ float bf2f(ushort_t u) {
    union { unsigned int i; float f; } v;
    v.i = ((unsigned int)u) << 16;
    return v.f;
}
__device__ __forceinline__ ushort_t f2bf(float f) {
    union { float f; unsigned int i; } v;
    v.f = f;
    unsigned int u = v.i;
    u += 0x7fffu + ((u >> 16) & 1u);   // round-to-nearest-even
    return (ushort_t)(u >> 16);
}
__device__ __forceinline__ float sigmoid_(float x) { return 1.f / (1.f + __expf(-x)); }
__device__ __forceinline__ float tanh_fast(float x) {
    // 1 - 2/(e^{2x}+1); exp overflow -> inf -> 1 (correct saturation)
    return 1.f - 2.f / (__expf(2.f * x) + 1.f);
}
__device__ __forceinline__ float mish_fast(float v) {
    // v * tanh(softplus(v)) == v * t/(t+2), t = e*(e+2), e = exp(v) (exact)
    float e = __expf(fminf(v, 20.f));
    float t = e * (e + 2.f);
    return v * t / (t + 2.f);
}

// ---------------------------------------------------------------------------
// fp32 -> bf16 bulk convert, 8 elems/thread.
// ---------------------------------------------------------------------------
__global__ __launch_bounds__(256) void cvt_bf16_kernel(
    const float* __restrict__ src, ushort_t* __restrict__ dst, int n8)
{
    int i = blockIdx.x * 256 + threadIdx.x;
    if (i >= n8) return;
    const float4* s = (const float4*)src;
    float4 a = s[i * 2];
    float4 b = s[i * 2 + 1];
    ushort8 v;
    v[0] = f2bf(a.x); v[1] = f2bf(a.y); v[2] = f2bf(a.z); v[3] = f2bf(a.w);
    v[4] = f2bf(b.x); v[5] = f2bf(b.y); v[6] = f2bf(b.z); v[7] = f2bf(b.w);
    ((ushort8*)dst)[i] = v;
}

// ---------------------------------------------------------------------------
// Init: hp0 = bf16(hx[:,0,:]); b_comb = b_ih + b_hh; zero group flags.
// ---------------------------------------------------------------------------
__global__ __launch_bounds__(256) void init_kernel(
    const float* __restrict__ hx,
    const float* __restrict__ b_ih, const float* __restrict__ b_hh,
    ushort_t* __restrict__ hp0, float* __restrict__ b_comb,
    unsigned* __restrict__ flags)
{
    int idx = blockIdx.x * 256 + threadIdx.x;   // over NB*HH
    int m = idx >> 9;
    int h = idx & 511;
    hp0[idx] = f2bf(hx[(size_t)m * TT * HH + h]);
    if (idx < 4 * HH) b_comb[idx] = b_ih[idx] + b_hh[idx];
    if (idx < RBLK * 16) flags[idx] = 0u;   // 256 flags, 64 B apart
}

// ---------------------------------------------------------------------------
// LDS-tiled bf16 GEMM: C[M,N] = A[M,512] * B[N,512]^T + bias, 128x128 tiles.
// bm = bx & 255 (A-tile), bn = bx >> 8 -> bn-siblings stride-256 = same XCD,
// so an A-tile is fetched from HBM once per XCD.
// MODE 0: scatter-store bf16 Gx[t][n][col] (A-row = n*128+t), bias=b_comb.
// MODE 1: out fp32 = mish(acc + bias) straight store.
// ---------------------------------------------------------------------------
template<int MODE>
__global__ __launch_bounds__(256, 2) void gemm_kernel(
    const ushort_t* __restrict__ A, const ushort_t* __restrict__ B,
    const float* __restrict__ bias,
    ushort_t* __restrict__ gx_lo, ushort_t* __restrict__ gx_hi,
    float* __restrict__ outp)
{
    __shared__ ushort_t As[128 * 32];
    __shared__ ushort_t Bs[128 * 32];
    const int tid  = threadIdx.x;
    const int wv   = tid >> 6;
    const int lane = tid & 63;
    const int q    = lane >> 4;
    const int l15  = lane & 15;
    const int bm   = blockIdx.x & 255;
    const int bn   = blockIdx.x >> 8;
    const int mh   = (wv >> 1) * 64;
    const int nh   = (wv & 1) * 64;

    const ushort_t* Ab = A + (size_t)bm * 128 * 512;
    const ushort_t* Bb = B + (size_t)bn * 128 * 512;

    const int r0 = tid >> 2;        // 0..63
    const int r1 = r0 + 64;         // 64..127
    const int k8 = (tid & 3) * 8;

    floatx4 acc[4][4];
#pragma unroll
    for (int i = 0; i < 4; ++i)
#pragma unroll
        for (int j = 0; j < 4; ++j) acc[i][j] = (floatx4){0.f, 0.f, 0.f, 0.f};

    for (int kt = 0; kt < 16; ++kt) {
        const int kc = kt * 32 + k8;
        short8 a0 = *(const short8*)(Ab + (size_t)r0 * 512 + kc);
        short8 a1 = *(const short8*)(Ab + (size_t)r1 * 512 + kc);
        short8 b0 = *(const short8*)(Bb + (size_t)r0 * 512 + kc);
        short8 b1 = *(const short8*)(Bb + (size_t)r1 * 512 + kc);
        __syncthreads();
        *(short8*)&As[r0 * 32 + k8] = a0;
        *(short8*)&As[r1 * 32 + k8] = a1;
        *(short8*)&Bs[r0 * 32 + k8] = b0;
        *(short8*)&Bs[r1 * 32 + k8] = b1;
        __syncthreads();
        short8 af[4], bfr[4];
#pragma unroll
        for (int s = 0; s < 4; ++s) af[s]  = *(const short8*)&As[(mh + s * 16 + l15) * 32 + q * 8];
#pragma unroll
        for (int s = 0; s < 4; ++s) bfr[s] = *(const short8*)&Bs[(nh + s * 16 + l15) * 32 + q * 8];
#pragma unroll
        for (int i = 0; i < 4; ++i)
#pragma unroll
            for (int j = 0; j < 4; ++j)
                acc[i][j] = __builtin_amdgcn_mfma_f32_16x16x32_bf16(af[i], bfr[j], acc[i][j], 0, 0, 0);
    }

    float bv[4];
#pragma unroll
    for (int j = 0; j < 4; ++j) bv[j] = bias[bn * 128 + nh + j * 16 + l15];

#pragma unroll
    for (int i = 0; i < 4; ++i) {
        const int rowb = bm * 128 + mh + i * 16 + q * 4;
#pragma unroll
        for (int r = 0; r < 4; ++r) {
            const int row = rowb + r;
            if (MODE == 0) {
                const int n = row >> 7, t = row & 127;
                ushort_t* base = (t < 64) ? (gx_lo + ((size_t)t * NB + n) * 2048)
                                          : (gx_hi + ((size_t)(t - 64) * NB + n) * 2048);
#pragma unroll
                for (int j = 0; j < 4; ++j)
                    base[bn * 128 + nh + j * 16 + l15] = f2bf(acc[i][j][r] + bv[j]);
            } else {
                float* ob = outp + (size_t)row * 512;
#pragma unroll
                for (int j = 0; j < 4; ++j)
                    ob[bn * 128 + nh + j * 16 + l15] = mish_fast(acc[i][j][r] + bv[j]);
            }
        }
    }
}

// ---------------------------------------------------------------------------
// Persistent recurrence, per-group flag sync, NO cache-maintenance fences.
//
// Round-1 post-mortem: the 14.8us/step cost was NOT the barrier mechanism --
// it was the per-step agent fence pair (buffer_wbl2 = writeback 4MiB L2,
// buffer_inv = invalidate L2) plus the refetch misses the invalidation
// causes. We exchange only 256KB/step; flushing 32MB of L2 for that is the
// bottleneck.
//
// New protocol -- targeted coherence via cache-bypassing ops, zero fences:
//   producer: h stores as RELAXED SYSTEM atomics (global_store sc0 sc1,
//     write-through to L3, the device coherence point). __syncthreads()
//     drains every wave's stores (compiler emits s_waitcnt vmcnt(0) before
//     s_barrier), so all h stores are ack'd at L3 before tid0 publishes
//     flag[block]=t+1 (also a relaxed sc0 sc1 store; own cacheline).
//   consumer: lanes 0..15 poll the 16 group flags with relaxed sc0 sc1
//     loads (bypass L1/L2, read L3 directly) -> __syncthreads -> stage the
//     h tile with relaxed 8B SYSTEM atomic loads (bypass L1/L2).
// Nothing cross-block-visible is ever dirty-in-L2, so no wbl2; nothing is
// read through L1/L2, so no inv. Read-only data (Gx, is_init, W_hh) now
// stays cache-resident across all 128 steps.
// ---------------------------------------------------------------------------
__global__ __launch_bounds__(256, 1) void recur_kernel(
    const float* __restrict__ Whh,       // (2048,512) fp32
    const int* __restrict__ is_init,     // (NB,TT)
    const float* __restrict__ cx,        // (NB,TT,HH) fp32
    const ushort_t* __restrict__ gx_lo,  // (64,NB,2048) bf16
    const ushort_t* __restrict__ gx_hi,  // (64,NB,2048) bf16
    ushort_t* __restrict__ hp0,          // (NB,HH) bf16: h0 in, h_T out
    ushort_t* __restrict__ hsb,          // (NB,TT,HH) bf16 all h_t
    float* __restrict__ c_out,           // (NB,HH) fp32 final c
    unsigned* __restrict__ flags)        // RBLK flags, 64 B apart
{
    __shared__ ushort_t hA[16 * 520];        // pad: row stride 520 shorts
    __shared__ float gbuf[4][16][32];

    const int tid  = threadIdx.x;
    const int gate = tid >> 6;
    const int lane = tid & 63;
    const int q    = lane >> 4;
    const int l15  = lane & 15;
    const int bm   = blockIdx.x >> 4;     // group: 0..15
    const int bh   = blockIdx.x & 15;     // member within group
    const int h0   = bh * 32;

    // ---- preload W_hh B-fragments (fp32 -> bf16) into registers: 128 VGPRs
    short8 bfrag[2][16];
#pragma unroll
    for (int j = 0; j < 2; ++j) {
        const float* wr = Whh + (size_t)(gate * 512 + h0 + j * 16 + l15) * 512;
#pragma unroll
        for (int kk = 0; kk < 16; ++kk) {
            const float* p = wr + kk * 32 + q * 8;
            float4 f0 = *(const float4*)p;
            float4 f1 = *(const float4*)(p + 4);
            short8 v;
            v[0] = (short)f2bf(f0.x); v[1] = (short)f2bf(f0.y);
            v[2] = (short)f2bf(f0.z); v[3] = (short)f2bf(f0.w);
            v[4] = (short)f2bf(f1.x); v[5] = (short)f2bf(f1.y);
            v[6] = (short)f2bf(f1.z); v[7] = (short)f2bf(f1.w);
            bfrag[j][kk] = v;
        }
    }

    // ---- c-state in registers: thread owns elems (n_c, h0+hc), (n_c, h0+hc+1)
    const int m_c = tid >> 4;             // 0..15
    const int hc  = (tid * 2) & 31;       // 0,2,..,30
    const int n_c = bm * 16 + m_c;
    float2 c2 = *(const float2*)(cx + (size_t)n_c * TT * HH + h0 + hc);

    unsigned* myflag = flags + (size_t)blockIdx.x * 16;

    for (int t = 0; t < TT; ++t) {
        // prefetch this step's Gx early (read-only, cached; written before
        // this kernel launched)
        const ushort_t* gxp = ((t < 64) ? (gx_lo + (size_t)t * NB * 2048)
                                        : (gx_hi + (size_t)(t - 64) * NB * 2048))
                              + (size_t)n_c * 2048 + h0 + hc;
        ushort2 gxu[4];
#pragma unroll
        for (int g = 0; g < 4; ++g) gxu[g] = *(const ushort2*)(gxp + g * 512);

        // ---- wait for the 16 group peers to have published h_{t-1}
        if (t > 0) {
            if (tid < 16) {
                const unsigned* fp = flags + (size_t)(bm * 16 + tid) * 16;
                while (__hip_atomic_load(fp, __ATOMIC_RELAXED,
                                         __HIP_MEMORY_SCOPE_SYSTEM) < (unsigned)t)
                    __builtin_amdgcn_s_sleep(1);
            }
            __syncthreads();
            __builtin_amdgcn_sched_barrier(0);   // no hoisting above the wait
        }

        // stage h-tile (16 x 512) to LDS via coherent (L1/L2-bypass) loads,
        // rows zeroed where is_init==1
#pragma unroll
        for (int i = 0; i < 4; ++i) {
            int idx = i * 256 + tid;
            int row = idx >> 6;
            int cc  = (idx & 63) * 8;
            int n   = bm * 16 + row;
            unsigned long long v0 = 0ull, v1 = 0ull;
            if (!is_init[n * TT + t]) {
                const unsigned long long* p = (const unsigned long long*)
                    (t ? (hsb + ((size_t)n * TT + (t - 1)) * HH + cc)
                       : (hp0 + (size_t)n * HH + cc));
                v0 = __hip_atomic_load(p,     __ATOMIC_RELAXED, __HIP_MEMORY_SCOPE_SYSTEM);
                v1 = __hip_atomic_load(p + 1, __ATOMIC_RELAXED, __HIP_MEMORY_SCOPE_SYSTEM);
            }
            *(unsigned long long*)&hA[row * 520 + cc]     = v0;
            *(unsigned long long*)&hA[row * 520 + cc + 4] = v1;
        }
        __syncthreads();

        floatx4 a0 = {0.f, 0.f, 0.f, 0.f}, a1 = {0.f, 0.f, 0.f, 0.f};
#pragma unroll
        for (int kk = 0; kk < 16; ++kk) {
            short8 af = *(const short8*)&hA[l15 * 520 + kk * 32 + q * 8];
            a0 = __builtin_amdgcn_mfma_f32_16x16x32_bf16(af, bfrag[0][kk], a0, 0, 0, 0);
            a1 = __builtin_amdgcn_mfma_f32_16x16x32_bf16(af, bfrag[1][kk], a1, 0, 0, 0);
        }
#pragma unroll
        for (int r = 0; r < 4; ++r) {
            gbuf[gate][q * 4 + r][l15]      = a0[r];
            gbuf[gate][q * 4 + r][16 + l15] = a1[r];
        }
        __syncthreads();

        // pointwise cell update for this thread's 2 elements
        float g4[4][2];
#pragma unroll
        for (int g = 0; g < 4; ++g) {
            g4[g][0] = bf2f(gxu[g].x) + gbuf[g][m_c][hc];
            g4[g][1] = bf2f(gxu[g].y) + gbuf[g][m_c][hc + 1];
        }
        const int rst = is_init[n_c * TT + t];
        float cp0 = rst ? 0.f : c2.x;
        float cp1 = rst ? 0.f : c2.y;
        float cn0 = sigmoid_(g4[1][0]) * cp0 + sigmoid_(g4[0][0]) * tanh_fast(g4[2][0]);
        float cn1 = sigmoid_(g4[1][1]) * cp1 + sigmoid_(g4[0][1]) * tanh_fast(g4[2][1]);
        float hn0 = sigmoid_(g4[3][0]) * tanh_fast(cn0);
        float hn1 = sigmoid_(g4[3][1]) * tanh_fast(cn1);
        c2.x = cn0; c2.y = cn1;

        // publish h_t: write-through to L3 (sc0 sc1), no fence needed
        unsigned hb32 = (unsigned)f2bf(hn0) | ((unsigned)f2bf(hn1) << 16);
        __hip_atomic_store((unsigned*)(hsb + ((size_t)n_c * TT + t) * HH + h0 + hc),
                           hb32, __ATOMIC_RELAXED, __HIP_MEMORY_SCOPE_SYSTEM);
        if (t == TT - 1) {
            ushort2 hb; hb.x = (ushort_t)(hb32 & 0xffffu); hb.y = (ushort_t)(hb32 >> 16);
            *(ushort2*)(hp0 + (size_t)n_c * HH + h0 + hc) = hb;   // final h for broadcast
        }

        // ---- flag this block's h_t as visible (skip after last step)
        if (t != TT - 1) {
            __syncthreads();   // compiler drains vmcnt(0) per wave before s_barrier
            if (tid == 0)
                __hip_atomic_store(myflag, (unsigned)(t + 1), __ATOMIC_RELAXED,
                                   __HIP_MEMORY_SCOPE_SYSTEM);
        }
    }

    // final c
    *(float2*)(c_out + (size_t)n_c * HH + h0 + hc) = c2;
}

// ---------------------------------------------------------------------------
// Broadcast h_T / c_T to (NB,TT,HH) fp32.
// ---------------------------------------------------------------------------
__global__ __launch_bounds__(256) void broadcast_kernel(
    const ushort_t* __restrict__ hT,   // (NB,HH) bf16
    const float* __restrict__ cT,      // (NB,HH) fp32
    float* __restrict__ h_rep, float* __restrict__ c_rep)
{
    size_t idx  = (size_t)blockIdx.x * 256 + threadIdx.x;
    size_t flat = idx * 8;
    int m = (int)(flat >> 16);
    int h = (int)(flat & 511);

    const ushort_t* hp = hT + (size_t)m * HH + h;
    const float*    cp = cT + (size_t)m * HH + h;

    float4 h0v, h1v, c0v, c1v;
    h0v.x = bf2f(hp[0]); h0v.y = bf2f(hp[1]); h0v.z = bf2f(hp[2]); h0v.w = bf2f(hp[3]);
    h1v.x = bf2f(hp[4]); h1v.y = bf2f(hp[5]); h1v.z = bf2f(hp[6]); h1v.w = bf2f(hp[7]);
    c0v.x = cp[0]; c0v.y = cp[1]; c0v.z = cp[2]; c0v.w = cp[3];
    c1v.x = cp[4]; c1v.y = cp[5]; c1v.z = cp[6]; c1v.w = cp[7];

    *(float4*)(h_rep + flat)     = h0v;
    *(float4*)(h_rep + flat + 4) = h1v;
    *(float4*)(c_rep + flat)     = c0v;
    *(float4*)(c_rep + flat + 4) = c1v;
}

// ---------------------------------------------------------------------------
extern "C" void kernel_launch(void* const* d_in, const int* in_sizes, int n_in,
                              void* d_out, int out_size, void* d_ws, size_t ws_size,
                              hipStream_t stream) {
    const float* x      = (const float*)d_in[0];
    const int*   isini  = (const int*)d_in[1];
    const float* hx     = (const float*)d_in[2];
    const float* cx     = (const float*)d_in[3];
    const float* W_ih   = (const float*)d_in[4];
    const float* W_hh   = (const float*)d_in[5];
    const float* b_ih   = (const float*)d_in[6];
    const float* b_hh   = (const float*)d_in[7];
    const float* W_out  = (const float*)d_in[8];
    const float* b_out  = (const float*)d_in[9];

    float* out   = (float*)d_out;
    float* h_rep = out + (size_t)NTH;
    float* c_rep = out + (size_t)2 * NTH;

    // Staging in dead d_out regions (stream-ordered overwrites):
    //  Gx (t<64)  -> out0 region  (consumed by recur; overwritten by outproj)
    //  Gx (t>=64) -> c_rep region (consumed by recur; overwritten by broadcast)
    //  hsb        -> h_rep lower half (written by recur; consumed by outproj)
    //  xb         -> h_rep upper half (consumed by Gx GEMM)
    ushort_t* gx_lo = (ushort_t*)out;
    ushort_t* gx_hi = (ushort_t*)c_rep;
    ushort_t* hsb   = (ushort_t*)h_rep;
    ushort_t* xb    = (ushort_t*)h_rep + (size_t)NTH;

    // workspace (~3.6 MiB)
    char* wsb = (char*)d_ws;
    ushort_t* hp0     = (ushort_t*)wsb;                                   // 256 KiB
    unsigned* flags   = (unsigned*)(wsb + (size_t)NB * HH * 2);           // 16 KiB
    float*    c_state = (float*)(wsb + (size_t)2 * NB * HH * 2);          // 512 KiB
    float*    b_comb  = (float*)(wsb + (size_t)2 * NB * HH * 2
                                     + (size_t)NB * HH * 4);              // 8 KiB
    ushort_t* woutb   = (ushort_t*)(wsb + (size_t)2 * NB * HH * 2
                                        + (size_t)NB * HH * 4 + 4 * HH * 4); // 512 KiB
    ushort_t* wihb    = woutb + (size_t)HH * HH;                          // 2 MiB

    // --- prep ---
    cvt_bf16_kernel<<<NTH / 8 / 256, 256, 0, stream>>>(x, xb, NTH / 8);
    cvt_bf16_kernel<<<4 * HH * II / 8 / 256, 256, 0, stream>>>(W_ih, wihb, 4 * HH * II / 8);
    cvt_bf16_kernel<<<HH * HH / 8 / 256, 256, 0, stream>>>(W_out, woutb, HH * HH / 8);
    init_kernel<<<NB * HH / 256, 256, 0, stream>>>(hx, b_ih, b_hh, hp0, b_comb, flags);

    // --- Gx = x @ W_ih^T + (b_ih + b_hh), bf16, layout (t, n, 2048) ---
    gemm_kernel<0><<<16 * 256, 256, 0, stream>>>(xb, wihb, b_comb, gx_lo, gx_hi, nullptr);

    // --- persistent recurrence, fence-free per-group flag sync ---
    recur_kernel<<<RBLK, 256, 0, stream>>>(W_hh, isini, cx, gx_lo, gx_hi,
                                           hp0, hsb, c_state, flags);

    // --- out0 = mish(hs @ W_out^T + b_out) ---
    gemm_kernel<1><<<4 * 256, 256, 0, stream>>>(hsb, woutb, b_out, nullptr, nullptr, out);

    // --- h_rep / c_rep broadcasts (final h in hp0) ---
    broadcast_kernel<<<NTH / 8 / 256, 256, 0, stream>>>(hp0, c_state, h_rep, c_rep);
}